// Round 3
// baseline (535.163 us; speedup 1.0000x reference)
//
#include <hip/hip_runtime.h>
#include <cstdint>
#include <cstddef>

typedef __attribute__((ext_vector_type(8))) short  short8;
typedef __attribute__((ext_vector_type(4))) short  short4v;
typedef __attribute__((ext_vector_type(4))) float  f32x4;

#define BZ   16
#define LQ   2048
#define LK   2048
#define DD   64
#define QBLK 64
#define KVB  128
#define NIT  (LK / KVB)

__device__ inline short f2bf(float f) {
    union { float f; uint32_t u; } x; x.f = f;
    uint32_t r = x.u + 0x7fffu + ((x.u >> 16) & 1u);   // RNE
    return (short)(r >> 16);
}

template<int CTRL>
__device__ inline float dppf(float x) {
    return __int_as_float(__builtin_amdgcn_update_dpp(0, __float_as_int(x), CTRL, 0xF, 0xF, false));
}
// reduce over the 16 lanes of a DPP row (our n-group)
__device__ inline float rmax16(float x) {
    x = fmaxf(x, dppf<0xB1>(x));    // quad_perm [1,0,3,2]  : xor1
    x = fmaxf(x, dppf<0x4E>(x));    // quad_perm [2,3,0,1]  : xor2
    x = fmaxf(x, dppf<0x124>(x));   // row_ror:4
    x = fmaxf(x, dppf<0x128>(x));   // row_ror:8
    return x;
}
__device__ inline float rsum16(float x) {
    x += dppf<0xB1>(x);
    x += dppf<0x4E>(x);
    x += dppf<0x124>(x);
    x += dppf<0x128>(x);
    return x;
}

__global__ __launch_bounds__(512, 4)
void attn_fwd(const float* __restrict__ Qg, const float* __restrict__ Kg,
              const float* __restrict__ Vg, const int* __restrict__ Mg,
              float* __restrict__ Og)
{
    __shared__ alignas(128) short Klds[KVB * DD];     // [kv][d], row=128B, XOR (d-part) swizzled
    __shared__ alignas(128) short Vtlds[DD * KVB];    // [d][kv], row=256B, XOR ((d&15)<<4) swizzled
    __shared__ alignas(128) short Plds[8][16 * 64];   // per-wave P
    __shared__ alignas(128) short Qlds[QBLK * DD];

    const int t = threadIdx.x;
    const int w = t >> 6;
    const int l = t & 63;
    const int g = l >> 4;
    const int n = l & 15;

    const int nb   = blockIdx.x;
    const int xcd  = nb & 7;
    const int jj   = nb >> 3;
    const int b    = xcd + 8 * (jj >> 5);
    const int qtl  = jj & 31;
    const int qbase = qtl * QBLK;

    const int stripe = w & 3;
    const int half   = w >> 2;

    const float* Qb = Qg + ((size_t)b * LQ + qbase) * DD;
    const float* Kb = Kg + (size_t)b * LK * DD;
    const float* Vb = Vg + (size_t)b * LK * DD;
    const int*   Mb = Mg + ((size_t)b * LQ + qbase) * (size_t)LK;

    const int sr = t >> 4;         // 0..31
    const int sc = (t & 15) * 4;   // d0 for K staging

    // ---- stage Q ----
    #pragma unroll
    for (int i = 0; i < 2; ++i) {
        int q = sr + i * 32;
        f32x4 qv = *(const f32x4*)(Qb + (size_t)q * DD + sc);
        short4v qp;
        qp.x = f2bf(qv.x); qp.y = f2bf(qv.y); qp.z = f2bf(qv.z); qp.w = f2bf(qv.w);
        *(short4v*)((char*)Qlds + q * 128 + ((sc * 2) ^ ((q & 7) << 4))) = qp;
    }
    __syncthreads();

    short8 aQ[2];
    {
        int qr = stripe * 16 + n;
        #pragma unroll
        for (int s = 0; s < 2; ++s)
            aQ[s] = *(short8*)((char*)Qlds + qr * 128 + ((s * 64 + g * 16) ^ ((qr & 7) << 4)));
    }

    f32x4 Oacc[4];
    #pragma unroll
    for (int c = 0; c < 4; ++c) { Oacc[c].x = 0.f; Oacc[c].y = 0.f; Oacc[c].z = 0.f; Oacc[c].w = 0.f; }
    float m2[4]   = { -1e30f, -1e30f, -1e30f, -1e30f };
    float lsum[4] = { 0.f, 0.f, 0.f, 0.f };

    const float SC2 = 0.125f * 1.4426950408889634f;

    f32x4 kr[4];
    float vv[4][4];                 // [p][e]: V[kvb + p*32 + w*4 + e][l]
    uint32_t mbits;

    auto load_kv = [&](int itx) {
        #pragma unroll
        for (int i = 0; i < 4; ++i) {
            int kv = sr + i * 32;
            kr[i] = *(const f32x4*)(Kb + (size_t)(itx * KVB + kv) * DD + sc);
        }
        #pragma unroll
        for (int p = 0; p < 4; ++p)
            #pragma unroll
            for (int e = 0; e < 4; ++e)
                vv[p][e] = Vb[(size_t)(itx * KVB + p * 32 + w * 4 + e) * DD + l];
    };
    auto load_mbits = [&](int itx) -> uint32_t {
        uint32_t bb = 0;
        const int* mp = Mb + (size_t)(stripe * 16 + g * 4) * LK + itx * KVB + half * 64 + n;
        #pragma unroll
        for (int r = 0; r < 4; ++r)
            #pragma unroll
            for (int c = 0; c < 4; ++c)
                bb |= (mp[(size_t)r * LK + c * 16] != 0) ? (1u << (r * 4 + c)) : 0u;
        return bb;
    };

    load_kv(0);
    mbits = load_mbits(0);

    for (int it = 0; it < NIT; ++it) {
        __syncthreads();   // A: previous compute done reading K/V LDS

        // ---- stage K ([kv][d] swizzled), vectorized b64 ----
        #pragma unroll
        for (int i = 0; i < 4; ++i) {
            int kv = sr + i * 32;
            short4v kp;
            kp.x = f2bf(kr[i].x); kp.y = f2bf(kr[i].y); kp.z = f2bf(kr[i].z); kp.w = f2bf(kr[i].w);
            *(short4v*)((char*)Klds + kv * 128 + ((sc * 2) ^ ((kv & 7) << 4))) = kp;
        }
        // ---- stage V ([d][kv] swizzled), 4 consecutive kv per b64 write ----
        #pragma unroll
        for (int p = 0; p < 4; ++p) {
            short4v vp;
            vp.x = f2bf(vv[p][0]); vp.y = f2bf(vv[p][1]);
            vp.z = f2bf(vv[p][2]); vp.w = f2bf(vv[p][3]);
            uint32_t byt = (uint32_t)l * 256u
                         + ((((uint32_t)(p * 32 + w * 4)) * 2u) ^ (((uint32_t)l & 15u) << 4));
            *(short4v*)((char*)Vtlds + byt) = vp;
        }
        __syncthreads();   // B: staging complete

        // ---- prefetch next tile's K/V into registers (hides HBM latency) ----
        int nx = (it + 1 < NIT) ? it + 1 : it;
        load_kv(nx);

        // ---- QK^T ----
        f32x4 S[4];
        #pragma unroll
        for (int c = 0; c < 4; ++c) { S[c].x = 0.f; S[c].y = 0.f; S[c].z = 0.f; S[c].w = 0.f; }
        __builtin_amdgcn_s_setprio(1);
        #pragma unroll
        for (int c = 0; c < 4; ++c) {
            int kvl = half * 64 + c * 16 + n;
            #pragma unroll
            for (int s = 0; s < 2; ++s) {
                short8 bK = *(short8*)((char*)Klds + kvl * 128
                                       + ((s * 64 + g * 16) ^ ((kvl & 7) << 4)));
                S[c] = __builtin_amdgcn_mfma_f32_16x16x32_bf16(aQ[s], bK, S[c], 0, 0, 0);
            }
        }
        __builtin_amdgcn_s_setprio(0);

        // ---- mask + scale in place ----
        #pragma unroll
        for (int c = 0; c < 4; ++c)
            #pragma unroll
            for (int r = 0; r < 4; ++r) {
                float x = S[c][r] * SC2;
                S[c][r] = ((mbits >> (r * 4 + c)) & 1u) ? -1.0e9f : x;
            }
        mbits = load_mbits(nx);   // prefetch next mask

        // ---- online softmax (DPP reduces, VALU pipe) ----
        #pragma unroll
        for (int r = 0; r < 4; ++r) {
            float mx = fmaxf(fmaxf(S[0][r], S[1][r]), fmaxf(S[2][r], S[3][r]));
            mx = rmax16(mx);
            float mnew = fmaxf(m2[r], mx);
            float resc = exp2f(m2[r] - mnew);
            m2[r] = mnew;
            lsum[r] *= resc;
            #pragma unroll
            for (int c = 0; c < 4; ++c) Oacc[c][r] *= resc;

            float rs = 0.f;
            int q = g * 4 + r;
            #pragma unroll
            for (int c = 0; c < 4; ++c) {
                float p = exp2f(S[c][r] - mnew);
                rs += p;
                *((short*)((char*)Plds[w] + q * 128
                           + (((c * 16 + n) * 2) ^ ((q & 7) << 4)))) = f2bf(p);
            }
            lsum[r] += rsum16(rs);
        }

        // ---- PV: Oacc += P[16][64] * V[64][64-d] ----
        __builtin_amdgcn_s_setprio(1);
        #pragma unroll
        for (int s = 0; s < 2; ++s) {
            short8 aP = *(short8*)((char*)Plds[w] + n * 128
                                   + ((s * 64 + g * 16) ^ ((n & 7) << 4)));
            #pragma unroll
            for (int c = 0; c < 4; ++c) {
                int d = c * 16 + n;
                short8 bV = *(short8*)((char*)Vtlds + d * 256
                                       + (((half * 128 + s * 64 + g * 16)) ^ ((d & 15) << 4)));
                Oacc[c] = __builtin_amdgcn_mfma_f32_16x16x32_bf16(aP, bV, Oacc[c], 0, 0, 0);
            }
        }
        __builtin_amdgcn_s_setprio(0);
    }

    // ---- merge kv-halves (wave pairs w, w^4) and store ----
    __syncthreads();
    float* mrg = (float*)Klds;     // 4 stripes x 16x64 f32 = 16 KB
    float* mlb = (float*)Vtlds;    // 64 rows x {m,l}

    if (half == 1) {
        #pragma unroll
        for (int r = 0; r < 4; ++r) {
            int qloc = g * 4 + r;
            int q = stripe * 16 + qloc;
            if (n == 0) { mlb[q * 2] = m2[r]; mlb[q * 2 + 1] = lsum[r]; }
            #pragma unroll
            for (int c = 0; c < 4; ++c)
                mrg[stripe * 1024 + qloc * 64 + c * 16 + n] = Oacc[c][r];
        }
    }
    __syncthreads();
    if (half == 0) {
        #pragma unroll
        for (int r = 0; r < 4; ++r) {
            int qloc = g * 4 + r;
            int q = stripe * 16 + qloc;
            float mB = mlb[q * 2], lB = mlb[q * 2 + 1];
            float ms = fmaxf(m2[r], mB);
            float sA = exp2f(m2[r] - ms);
            float sB = exp2f(mB - ms);
            float inv = 1.0f / (lsum[r] * sA + lB * sB);
            #pragma unroll
            for (int c = 0; c < 4; ++c) {
                float oB = mrg[stripe * 1024 + qloc * 64 + c * 16 + n];
                Og[((size_t)b * LQ + qbase + q) * DD + c * 16 + n] =
                    (Oacc[c][r] * sA + oB * sB) * inv;
            }
        }
    }
}

extern "C" void kernel_launch(void* const* d_in, const int* in_sizes, int n_in,
                              void* d_out, int out_size, void* d_ws, size_t ws_size,
                              hipStream_t stream) {
    const float* q = (const float*)d_in[0];
    const float* k = (const float*)d_in[1];
    const float* v = (const float*)d_in[2];
    const int*   m = (const int*)d_in[3];
    float* out = (float*)d_out;
    dim3 grid(BZ * (LQ / QBLK));
    dim3 block(512);
    attn_fwd<<<grid, block, 0, stream>>>(q, k, v, m, out);
}

// Round 5
// 480.772 us; speedup vs baseline: 1.1131x; 1.1131x over previous
//
#include <hip/hip_runtime.h>
#include <cstdint>
#include <cstddef>

typedef __attribute__((ext_vector_type(8))) short  short8;
typedef __attribute__((ext_vector_type(4))) short  short4v;
typedef __attribute__((ext_vector_type(4))) float  f32x4;

#define BZ   16
#define LQ   2048
#define LK   2048
#define DD   64
#define QBLK 64
#define KVB  128
#define NIT  (LK / KVB)

__device__ inline short f2bf(float f) {
    union { float f; uint32_t u; } x; x.f = f;
    uint32_t r = x.u + 0x7fffu + ((x.u >> 16) & 1u);   // RNE
    return (short)(r >> 16);
}

template<int CTRL>
__device__ inline float dppf(float x) {
    return __int_as_float(__builtin_amdgcn_update_dpp(0, __float_as_int(x), CTRL, 0xF, 0xF, false));
}
__device__ inline float rmax16(float x) {
    x = fmaxf(x, dppf<0xB1>(x));    // quad_perm xor1
    x = fmaxf(x, dppf<0x4E>(x));    // quad_perm xor2
    x = fmaxf(x, dppf<0x124>(x));   // row_ror:4
    x = fmaxf(x, dppf<0x128>(x));   // row_ror:8
    return x;
}
__device__ inline float rsum16(float x) {
    x += dppf<0xB1>(x);
    x += dppf<0x4E>(x);
    x += dppf<0x124>(x);
    x += dppf<0x128>(x);
    return x;
}

__global__ __launch_bounds__(512, 4)
void attn_fwd(const float* __restrict__ Qg, const float* __restrict__ Kg,
              const float* __restrict__ Vg, const int* __restrict__ Mg,
              float* __restrict__ Og)
{
    __shared__ alignas(128) short Klds[KVB * DD];     // [kv][d], row=128B, XOR swizzled
    __shared__ alignas(128) short Vtlds[DD * KVB];    // [d][kv], row=256B, XOR ((d&15)<<4)
    __shared__ alignas(128) short Plds[8][16 * 64];   // per-wave P
    __shared__ alignas(128) short Qlds[QBLK * DD];

    const int t = threadIdx.x;
    const int w = t >> 6;
    const int l = t & 63;
    const int g = l >> 4;
    const int n = l & 15;

    const int nb   = blockIdx.x;
    const int xcd  = nb & 7;
    const int jj   = nb >> 3;
    const int b    = xcd + 8 * (jj >> 5);
    const int qtl  = jj & 31;
    const int qbase = qtl * QBLK;

    const int stripe = w & 3;
    const int half   = w >> 2;

    const float* Qb = Qg + ((size_t)b * LQ + qbase) * DD;
    const float* Kb = Kg + (size_t)b * LK * DD;
    const float* Vb = Vg + (size_t)b * LK * DD;
    const int*   Mb = Mg + ((size_t)b * LQ + qbase) * (size_t)LK;

    const int sr = t >> 4;         // 0..31
    const int sc = (t & 15) * 4;   // d0 for K staging

    f32x4 kr[4];
    float vv[4][4];
    int   mv[16];
    uint32_t mbits = 0;

    const int*   mp0 = Mb + (size_t)(stripe * 16 + g * 4) * LK + half * 64 + n;
    const float* vp0 = Vb + (size_t)(w * 4) * DD + l;
    const float* kp0 = Kb + (size_t)sr * DD + sc;

    // ---- prologue: issue prefetch for tile 0, pinned by sched_barrier ----
    #pragma unroll
    for (int r = 0; r < 4; ++r)
        #pragma unroll
        for (int c = 0; c < 4; ++c)
            mv[r * 4 + c] = mp0[(size_t)r * LK + c * 16];
    #pragma unroll
    for (int i = 0; i < 4; ++i)
        kr[i] = *(const f32x4*)(kp0 + (size_t)(i * 32) * DD);
    #pragma unroll
    for (int p = 0; p < 4; ++p)
        #pragma unroll
        for (int e = 0; e < 4; ++e)
            vv[p][e] = vp0[(size_t)(p * 32 + e) * DD];
    __builtin_amdgcn_sched_barrier(0);

    // ---- stage Q (overlaps tile-0 prefetch) ----
    #pragma unroll
    for (int i = 0; i < 2; ++i) {
        int q = sr + i * 32;
        f32x4 qv = *(const f32x4*)(Qb + (size_t)q * DD + sc);
        short4v qp;
        qp.x = f2bf(qv.x); qp.y = f2bf(qv.y); qp.z = f2bf(qv.z); qp.w = f2bf(qv.w);
        *(short4v*)((char*)Qlds + q * 128 + ((sc * 2) ^ ((q & 7) << 4))) = qp;
    }
    __syncthreads();

    short8 aQ[2];
    {
        int qr = stripe * 16 + n;
        #pragma unroll
        for (int s = 0; s < 2; ++s)
            aQ[s] = *(short8*)((char*)Qlds + qr * 128 + ((s * 64 + g * 16) ^ ((qr & 7) << 4)));
    }

    f32x4 Oacc[4];
    #pragma unroll
    for (int c = 0; c < 4; ++c) { Oacc[c].x = 0.f; Oacc[c].y = 0.f; Oacc[c].z = 0.f; Oacc[c].w = 0.f; }
    float m2[4]   = { -1e30f, -1e30f, -1e30f, -1e30f };
    float lsum[4] = { 0.f, 0.f, 0.f, 0.f };

    const float SC2 = 0.125f * 1.4426950408889634f;

    for (int it = 0; it < NIT; ++it) {
        __syncthreads();   // A: prev compute done reading K/V LDS (drains vmcnt -> data ready)

        // ---- stage K ([kv][d] swizzled) from registers ----
        #pragma unroll
        for (int i = 0; i < 4; ++i) {
            int kv = sr + i * 32;
            short4v kp;
            kp.x = f2bf(kr[i].x); kp.y = f2bf(kr[i].y); kp.z = f2bf(kr[i].z); kp.w = f2bf(kr[i].w);
            *(short4v*)((char*)Klds + kv * 128 + ((sc * 2) ^ ((kv & 7) << 4))) = kp;
        }
        // ---- stage V ([d][kv] swizzled) from registers ----
        #pragma unroll
        for (int p = 0; p < 4; ++p) {
            short4v vp;
            vp.x = f2bf(vv[p][0]); vp.y = f2bf(vv[p][1]);
            vp.z = f2bf(vv[p][2]); vp.w = f2bf(vv[p][3]);
            uint32_t byt = (uint32_t)l * 256u
                         + ((((uint32_t)(p * 32 + w * 4)) * 2u) ^ (((uint32_t)l & 15u) << 4));
            *(short4v*)((char*)Vtlds + byt) = vp;
        }
        // ---- pack mask bits for tile it (frees mv) ----
        {
            uint32_t mb = 0;
            #pragma unroll
            for (int i = 0; i < 16; ++i) mb |= (mv[i] != 0) ? (1u << i) : 0u;
            mbits = mb;
        }
        __syncthreads();   // B: staging complete

        // ---- issue prefetch for tile it+1 (after B so barrier doesn't wait on it) ----
        if (it + 1 < NIT) {
            const int*   mp = mp0 + (size_t)(it + 1) * KVB;
            const float* kp = kp0 + (size_t)(it + 1) * KVB * DD;
            const float* vp = vp0 + (size_t)(it + 1) * KVB * DD;
            #pragma unroll
            for (int r = 0; r < 4; ++r)
                #pragma unroll
                for (int c = 0; c < 4; ++c)
                    mv[r * 4 + c] = mp[(size_t)r * LK + c * 16];
            #pragma unroll
            for (int i = 0; i < 4; ++i)
                kr[i] = *(const f32x4*)(kp + (size_t)(i * 32) * DD);
            #pragma unroll
            for (int p = 0; p < 4; ++p)
                #pragma unroll
                for (int e = 0; e < 4; ++e)
                    vv[p][e] = vp[(size_t)(p * 32 + e) * DD];
            __builtin_amdgcn_sched_barrier(0);
        }

        // ---- QK^T ----
        f32x4 S[4];
        #pragma unroll
        for (int c = 0; c < 4; ++c) { S[c].x = 0.f; S[c].y = 0.f; S[c].z = 0.f; S[c].w = 0.f; }
        __builtin_amdgcn_s_setprio(1);
        #pragma unroll
        for (int c = 0; c < 4; ++c) {
            int kvl = half * 64 + c * 16 + n;
            #pragma unroll
            for (int s = 0; s < 2; ++s) {
                short8 bK = *(short8*)((char*)Klds + kvl * 128
                                       + ((s * 64 + g * 16) ^ ((kvl & 7) << 4)));
                S[c] = __builtin_amdgcn_mfma_f32_16x16x32_bf16(aQ[s], bK, S[c], 0, 0, 0);
            }
        }
        __builtin_amdgcn_s_setprio(0);

        // ---- mask + scale in place ----
        #pragma unroll
        for (int c = 0; c < 4; ++c)
            #pragma unroll
            for (int r = 0; r < 4; ++r) {
                float x = S[c][r] * SC2;
                S[c][r] = ((mbits >> (r * 4 + c)) & 1u) ? -1.0e9f : x;
            }

        // ---- online softmax (DPP reduces) ----
        #pragma unroll
        for (int r = 0; r < 4; ++r) {
            float mx = fmaxf(fmaxf(S[0][r], S[1][r]), fmaxf(S[2][r], S[3][r]));
            mx = rmax16(mx);
            float mnew = fmaxf(m2[r], mx);
            float resc = exp2f(m2[r] - mnew);
            m2[r] = mnew;
            lsum[r] *= resc;
            #pragma unroll
            for (int c = 0; c < 4; ++c) Oacc[c][r] *= resc;

            float rs = 0.f;
            int q = g * 4 + r;
            #pragma unroll
            for (int c = 0; c < 4; ++c) {
                float p = exp2f(S[c][r] - mnew);
                rs += p;
                *((short*)((char*)Plds[w] + q * 128
                           + (((c * 16 + n) * 2) ^ ((q & 7) << 4)))) = f2bf(p);
            }
            lsum[r] += rsum16(rs);
        }

        // ---- PV ----
        __builtin_amdgcn_s_setprio(1);
        #pragma unroll
        for (int s = 0; s < 2; ++s) {
            short8 aP = *(short8*)((char*)Plds[w] + n * 128
                                   + ((s * 64 + g * 16) ^ ((n & 7) << 4)));
            #pragma unroll
            for (int c = 0; c < 4; ++c) {
                int d = c * 16 + n;
                short8 bV = *(short8*)((char*)Vtlds + d * 256
                                       + (((half * 128 + s * 64 + g * 16)) ^ ((d & 15) << 4)));
                Oacc[c] = __builtin_amdgcn_mfma_f32_16x16x32_bf16(aP, bV, Oacc[c], 0, 0, 0);
            }
        }
        __builtin_amdgcn_s_setprio(0);
    }

    // ---- merge kv-halves (wave pairs w, w^4) and store ----
    __syncthreads();
    float* mrg = (float*)Klds;
    float* mlb = (float*)Vtlds;

    if (half == 1) {
        #pragma unroll
        for (int r = 0; r < 4; ++r) {
            int qloc = g * 4 + r;
            int q = stripe * 16 + qloc;
            if (n == 0) { mlb[q * 2] = m2[r]; mlb[q * 2 + 1] = lsum[r]; }
            #pragma unroll
            for (int c = 0; c < 4; ++c)
                mrg[stripe * 1024 + qloc * 64 + c * 16 + n] = Oacc[c][r];
        }
    }
    __syncthreads();
    if (half == 0) {
        #pragma unroll
        for (int r = 0; r < 4; ++r) {
            int qloc = g * 4 + r;
            int q = stripe * 16 + qloc;
            float mB = mlb[q * 2], lB = mlb[q * 2 + 1];
            float ms = fmaxf(m2[r], mB);
            float sA = exp2f(m2[r] - ms);
            float sB = exp2f(mB - ms);
            float inv = 1.0f / (lsum[r] * sA + lB * sB);
            #pragma unroll
            for (int c = 0; c < 4; ++c) {
                float oB = mrg[stripe * 1024 + qloc * 64 + c * 16 + n];
                Og[((size_t)b * LQ + qbase + q) * DD + c * 16 + n] =
                    (Oacc[c][r] * sA + oB * sB) * inv;
            }
        }
    }
}

extern "C" void kernel_launch(void* const* d_in, const int* in_sizes, int n_in,
                              void* d_out, int out_size, void* d_ws, size_t ws_size,
                              hipStream_t stream) {
    const float* q = (const float*)d_in[0];
    const float* k = (const float*)d_in[1];
    const float* v = (const float*)d_in[2];
    const int*   m = (const int*)d_in[3];
    float* out = (float*)d_out;
    dim3 grid(BZ * (LQ / QBLK));
    dim3 block(512);
    attn_fwd<<<grid, block, 0, stream>>>(q, k, v, m, out);
}

// Round 6
// 475.316 us; speedup vs baseline: 1.1259x; 1.0115x over previous
//
#include <hip/hip_runtime.h>
#include <hip/hip_bf16.h>
#include <cstdint>
#include <cstddef>

typedef __attribute__((ext_vector_type(8))) short  short8;
typedef __attribute__((ext_vector_type(4))) short  short4v;
typedef __attribute__((ext_vector_type(4))) float  f32x4;
typedef __attribute__((ext_vector_type(4))) int    i32x4;

#define BZ   16
#define LQ   2048
#define LK   2048
#define DD   64
#define QBLK 64
#define KVB  64
#define NIT  (LK / KVB)          // 32

// ---------------- pass 1: pack int32 mask -> 1 bit/elem ----------------
__global__ __launch_bounds__(256)
void pack_mask(const int* __restrict__ m, uint32_t* __restrict__ out) {
    size_t t = (size_t)blockIdx.x * 256 + threadIdx.x;    // word index
    const i32x4* p = reinterpret_cast<const i32x4*>(m + t * 32);
    uint32_t w = 0;
    #pragma unroll
    for (int j = 0; j < 8; ++j) {
        i32x4 v = p[j];
        w |= (v.x != 0 ? 1u : 0u) << (j * 4 + 0);
        w |= (v.y != 0 ? 1u : 0u) << (j * 4 + 1);
        w |= (v.z != 0 ? 1u : 0u) << (j * 4 + 2);
        w |= (v.w != 0 ? 1u : 0u) << (j * 4 + 3);
    }
    out[t] = w;
}

// ---------------- helpers ----------------
__device__ inline short bfs(float f) {                    // f32 -> bf16 bits (compiler pairs into cvt_pk)
    __hip_bfloat16 h = __float2bfloat16(f);
    union { __hip_bfloat16 h; short s; } u; u.h = h; return u.s;
}

template<int CTRL>
__device__ inline float dppf(float x) {
    return __int_as_float(__builtin_amdgcn_update_dpp(0, __float_as_int(x), CTRL, 0xF, 0xF, false));
}
__device__ inline float rmax16(float x) {
    x = fmaxf(x, dppf<0xB1>(x));    // quad_perm xor1
    x = fmaxf(x, dppf<0x4E>(x));    // quad_perm xor2
    x = fmaxf(x, dppf<0x124>(x));   // row_ror:4
    x = fmaxf(x, dppf<0x128>(x));   // row_ror:8
    return x;
}
__device__ inline float rsum16(float x) {
    x += dppf<0xB1>(x);
    x += dppf<0x4E>(x);
    x += dppf<0x124>(x);
    x += dppf<0x128>(x);
    return x;
}

__device__ inline void glds16(const float* gp, void* lp) {
    __builtin_amdgcn_global_load_lds(
        (const __attribute__((address_space(1))) void*)(gp),
        (__attribute__((address_space(3))) void*)(lp),
        16, 0, 0);
}

// ---------------- pass 2: attention ----------------
__global__ __launch_bounds__(256, 2)
void attn_fwd(const float* __restrict__ Qg, const float* __restrict__ Kg,
              const float* __restrict__ Vg, const uint32_t* __restrict__ MW,
              float* __restrict__ Og)
{
    __shared__ alignas(128) float Kbuf[2][KVB * DD];   // f32, linear rows, source pair-XOR swizzled
    __shared__ alignas(128) float Vbuf[2][KVB * DD];
    __shared__ alignas(128) short PQ[4][16 * 64];      // per-wave: Q rows (prologue) then P (loop)

    const int t = threadIdx.x;
    const int w = t >> 6;          // wave 0..3, owns q-rows w*16..w*16+15
    const int l = t & 63;
    const int g = l >> 4;          // 0..3
    const int n = l & 15;

    const int nb   = blockIdx.x;
    const int xcd  = nb & 7;
    const int jj   = nb >> 3;
    const int b    = xcd + 8 * (jj >> 5);
    const int qtl  = jj & 31;
    const int qbase = qtl * QBLK;

    const float* Qb = Qg + ((size_t)b * LQ + qbase) * DD;
    const float* Kb = Kg + (size_t)b * LK * DD;
    const float* Vb = Vg + (size_t)b * LK * DD;
    const uint32_t* mwp = MW + ((size_t)b * LQ + qbase) * 64;   // 64 words per q-row

    // ---- glds stage of tile `it` into buf `sel` (fire-and-forget, unsinkable) ----
    auto stage = [&](int it, int sel) {
        #pragma unroll
        for (int s = 0; s < 4; ++s) {
            int CH  = s * 4 + w;                 // chunk 0..15, wave-uniform
            int kv  = CH * 4 + g;                // row this lane feeds
            int psw = (kv & 7) ^ (kv >> 3);      // 32B-pair XOR swizzle
            size_t go = (size_t)(it * KVB + kv) * DD + (size_t)((((n >> 1) ^ psw) * 8) + (n & 1) * 4);
            glds16(Kb + go, (void*)&Kbuf[sel][CH * 256]);
            glds16(Vb + go, (void*)&Vbuf[sel][CH * 256]);
        }
    };

    // ---- prologue: glds tile 0; stage Q (f32->bf16, swizzled) ----
    stage(0, 0);
    {
        int qr = t >> 2;                // 0..63
        int db = (t & 3) * 16;
        short* row = &PQ[qr >> 4][(qr & 15) * 64];
        #pragma unroll
        for (int k2 = 0; k2 < 4; ++k2) {
            f32x4 qv = *(const f32x4*)(Qb + (size_t)qr * DD + db + k2 * 4);
            int dd = db + k2 * 4;
            short4v qp;
            qp.x = bfs(qv.x); qp.y = bfs(qv.y); qp.z = bfs(qv.z); qp.w = bfs(qv.w);
            *(short4v*)((char*)row + ((dd * 2) ^ ((qr & 7) << 4))) = qp;
        }
    }
    __syncthreads();   // Q staged; glds(0) drained by barrier's vmcnt(0)

    // ---- hoist Q A-fragments (rows w*16+n) ----
    short8 aQ[2];
    {
        short* row = &PQ[w][n * 64];
        #pragma unroll
        for (int s = 0; s < 2; ++s)
            aQ[s] = *(short8*)((char*)row + ((s * 64 + g * 16) ^ ((n & 7) << 4)));
    }

    f32x4 Oacc[4];
    #pragma unroll
    for (int c = 0; c < 4; ++c) { Oacc[c].x = 0.f; Oacc[c].y = 0.f; Oacc[c].z = 0.f; Oacc[c].w = 0.f; }
    float m2[4]   = { -1e30f, -1e30f, -1e30f, -1e30f };
    float lsum[4] = { 0.f, 0.f, 0.f, 0.f };

    const float SC2 = 0.125f * 1.4426950408889634f;   // 1/sqrt(64)*log2(e)
    short* Pw = &PQ[w][0];                            // P overlays dead Q slice (same wave's region)

    for (int it = 0; it < NIT; ++it) {
        const int cur = it & 1;
        if (it + 1 < NIT) stage(it + 1, cur ^ 1);     // async: flies under this iter's compute

        // ---- mask words (broadcast across n-lanes; 2 words = 64 kv bits per row) ----
        uint32_t mw0[4], mw1[4];
        #pragma unroll
        for (int r = 0; r < 4; ++r) {
            uint2 v = *(const uint2*)(mwp + (size_t)(w * 16 + g * 4 + r) * 64 + it * 2);
            mw0[r] = v.x; mw1[r] = v.y;
        }

        // ---- QK^T from Kbuf[cur] (f32 frags -> bf16) ----
        f32x4 S[4];
        #pragma unroll
        for (int c = 0; c < 4; ++c) { S[c].x = 0.f; S[c].y = 0.f; S[c].z = 0.f; S[c].w = 0.f; }
        __builtin_amdgcn_s_setprio(1);
        #pragma unroll
        for (int c = 0; c < 4; ++c) {
            int kvl = c * 16 + n;
            int psw = (kvl & 7) ^ (kvl >> 3);
            #pragma unroll
            for (int s = 0; s < 2; ++s) {
                const char* bp = (const char*)&Kbuf[cur][kvl * 64] + (((s * 4 + g) ^ psw) * 32);
                f32x4 h0 = *(const f32x4*)bp;
                f32x4 h1 = *(const f32x4*)(bp + 16);
                short8 bk;
                bk[0] = bfs(h0.x); bk[1] = bfs(h0.y); bk[2] = bfs(h0.z); bk[3] = bfs(h0.w);
                bk[4] = bfs(h1.x); bk[5] = bfs(h1.y); bk[6] = bfs(h1.z); bk[7] = bfs(h1.w);
                S[c] = __builtin_amdgcn_mfma_f32_16x16x32_bf16(aQ[s], bk, S[c], 0, 0, 0);
            }
        }
        __builtin_amdgcn_s_setprio(0);

        // ---- mask + scale ----
        #pragma unroll
        for (int c = 0; c < 4; ++c)
            #pragma unroll
            for (int r = 0; r < 4; ++r) {
                uint32_t mword = (c & 2) ? mw1[r] : mw0[r];
                uint32_t bit = (mword >> ((c & 1) * 16 + n)) & 1u;
                float x = S[c][r] * SC2;
                S[c][r] = bit ? -1.0e9f : x;
            }

        // ---- online softmax (DPP reduces over 16 n-lanes = full 64 kv with in-reg fmax) ----
        #pragma unroll
        for (int r = 0; r < 4; ++r) {
            float mx = fmaxf(fmaxf(S[0][r], S[1][r]), fmaxf(S[2][r], S[3][r]));
            mx = rmax16(mx);
            float mnew = fmaxf(m2[r], mx);
            float resc = exp2f(m2[r] - mnew);
            m2[r] = mnew;
            lsum[r] *= resc;
            #pragma unroll
            for (int c = 0; c < 4; ++c) Oacc[c][r] *= resc;

            float rs = 0.f;
            int q_ = g * 4 + r;
            #pragma unroll
            for (int c = 0; c < 4; ++c) {
                float p = exp2f(S[c][r] - mnew);
                rs += p;
                *((short*)((char*)Pw + q_ * 128 + (((c * 16 + n) * 2) ^ ((q_ & 7) << 4)))) = bfs(p);
            }
            lsum[r] += rsum16(rs);
        }

        // ---- PV: Oacc += P[16][64] x V[64][64] from Vbuf[cur] ----
        __builtin_amdgcn_s_setprio(1);
        #pragma unroll
        for (int ks = 0; ks < 2; ++ks) {
            short8 aP = *(short8*)((char*)Pw + n * 128 + ((ks * 64 + g * 16) ^ ((n & 7) << 4)));
            #pragma unroll
            for (int c = 0; c < 4; ++c) {
                float ve[8];
                #pragma unroll
                for (int e = 0; e < 8; ++e) {
                    int kve = ks * 32 + g * 8 + e;
                    int pswv = e ^ (ks * 4 + g);              // (kve&7)^(kve>>3)
                    const char* p = (const char*)&Vbuf[cur][kve * 64]
                                  + ((((c * 2) + (n >> 3)) ^ pswv) * 32)
                                  + ((n >> 2) & 1) * 16 + (n & 3) * 4;
                    ve[e] = *(const float*)p;
                }
                short8 bv;
                bv[0] = bfs(ve[0]); bv[1] = bfs(ve[1]); bv[2] = bfs(ve[2]); bv[3] = bfs(ve[3]);
                bv[4] = bfs(ve[4]); bv[5] = bfs(ve[5]); bv[6] = bfs(ve[6]); bv[7] = bfs(ve[7]);
                Oacc[c] = __builtin_amdgcn_mfma_f32_16x16x32_bf16(aP, bv, Oacc[c], 0, 0, 0);
            }
        }
        __builtin_amdgcn_s_setprio(0);

        __syncthreads();   // one barrier/iter: readers of bufs[cur] done; glds(it+1) drained
    }

    // ---- normalize + store (no merge needed; wave owns full rows) ----
    #pragma unroll
    for (int r = 0; r < 4; ++r) {
        float inv = 1.0f / lsum[r];
        #pragma unroll
        for (int c = 0; c < 4; ++c)
            Og[((size_t)b * LQ + qbase + w * 16 + g * 4 + r) * DD + c * 16 + n] = Oacc[c][r] * inv;
    }
}

extern "C" void kernel_launch(void* const* d_in, const int* in_sizes, int n_in,
                              void* d_out, int out_size, void* d_ws, size_t ws_size,
                              hipStream_t stream) {
    const float* q = (const float*)d_in[0];
    const float* k = (const float*)d_in[1];
    const float* v = (const float*)d_in[2];
    const int*   m = (const int*)d_in[3];
    float* out = (float*)d_out;
    uint32_t* mw = (uint32_t*)d_ws;                    // 16*2048*2048/32 words = 8 MB

    pack_mask<<<dim3((BZ * LQ * (LK / 32)) / 256), dim3(256), 0, stream>>>(m, mw);
    attn_fwd<<<dim3(BZ * (LQ / QBLK)), dim3(256), 0, stream>>>(q, k, v, mw, out);
}

// Round 8
// 401.088 us; speedup vs baseline: 1.3343x; 1.1851x over previous
//
#include <hip/hip_runtime.h>
#include <hip/hip_bf16.h>
#include <cstdint>
#include <cstddef>

typedef __attribute__((ext_vector_type(8))) short  short8;
typedef __attribute__((ext_vector_type(4))) short  short4v;
typedef __attribute__((ext_vector_type(4))) float  f32x4;

#define BZ   16
#define LQ   2048
#define LK   2048
#define DD   64
#define QBLK 64
#define KVB  64
#define NIT  (LK / KVB)          // 32

__device__ inline short bfs(float f) {
    union { float f; uint32_t u; } x; x.f = f;
    uint32_t r = x.u + 0x7fffu + ((x.u >> 16) & 1u);   // RNE
    return (short)(r >> 16);
}

template<int CTRL>
__device__ inline float dppf(float x) {
    return __int_as_float(__builtin_amdgcn_update_dpp(0, __float_as_int(x), CTRL, 0xF, 0xF, false));
}
__device__ inline float rmax16(float x) {
    x = fmaxf(x, dppf<0xB1>(x));    // quad_perm xor1
    x = fmaxf(x, dppf<0x4E>(x));    // quad_perm xor2
    x = fmaxf(x, dppf<0x124>(x));   // row_ror:4
    x = fmaxf(x, dppf<0x128>(x));   // row_ror:8
    return x;
}
__device__ inline float rsum16(float x) {
    x += dppf<0xB1>(x);
    x += dppf<0x4E>(x);
    x += dppf<0x124>(x);
    x += dppf<0x128>(x);
    return x;
}

__device__ inline void glds16(const void* gp, void* lp) {
    __builtin_amdgcn_global_load_lds(
        (const __attribute__((address_space(1))) void*)gp,
        (__attribute__((address_space(3))) void*)lp, 16, 0, 0);
}

// ---------------- pass 1: K,V f32 -> bf16 tiles, pre-swizzled; V transposed ----------------
// Tile blk = b*32+it covers kv rows it*64..+63. Output tiles are 8KB contiguous.
// K tile layout:  [kv][d] bf16, row 128B, granule(16B) index ^= (kv&7)
// V^T tile layout:[d][kv] bf16, row 128B, granule index ^= (d&7)
__global__ __launch_bounds__(256)
void prep_kv(const float* __restrict__ K, const float* __restrict__ V,
             short* __restrict__ Ko, short* __restrict__ Vo)
{
    __shared__ float T[64 * 65];
    const int blk = blockIdx.x;
    const int t = threadIdx.x;
    const int row = t >> 2;              // 0..63
    const int c4  = (t & 3) * 16;        // 0,16,32,48
    const float* Ks = K + (size_t)blk * 4096;
    const float* Vs = V + (size_t)blk * 4096;
    char* Kt = (char*)Ko + (size_t)blk * 8192;
    char* Vt = (char*)Vo + (size_t)blk * 8192;

    #pragma unroll
    for (int h = 0; h < 2; ++h) {
        f32x4 a = *(const f32x4*)(Ks + row * 64 + c4 + h * 8);
        f32x4 b = *(const f32x4*)(Ks + row * 64 + c4 + h * 8 + 4);
        short8 o;
        o[0] = bfs(a.x); o[1] = bfs(a.y); o[2] = bfs(a.z); o[3] = bfs(a.w);
        o[4] = bfs(b.x); o[5] = bfs(b.y); o[6] = bfs(b.z); o[7] = bfs(b.w);
        int gr = (c4 >> 3) + h;
        *(short8*)(Kt + row * 128 + ((gr ^ (row & 7)) * 16)) = o;
    }
    #pragma unroll
    for (int j = 0; j < 4; ++j) {
        f32x4 v4 = *(const f32x4*)(Vs + row * 64 + c4 + j * 4);
        T[row * 65 + c4 + j * 4 + 0] = v4.x;
        T[row * 65 + c4 + j * 4 + 1] = v4.y;
        T[row * 65 + c4 + j * 4 + 2] = v4.z;
        T[row * 65 + c4 + j * 4 + 3] = v4.w;
    }
    __syncthreads();
    #pragma unroll
    for (int h = 0; h < 2; ++h) {        // out-row d=row, kv granules from c4
        short8 o;
        #pragma unroll
        for (int e = 0; e < 8; ++e)
            o[e] = bfs(T[(c4 + h * 8 + e) * 65 + row]);
        int gr = (c4 >> 3) + h;
        *(short8*)(Vt + row * 128 + ((gr ^ (row & 7)) * 16)) = o;
    }
}

// ---------------- pass 2: attention ----------------
__global__ __launch_bounds__(256, 2)
void attn_fwd(const float* __restrict__ Qg, const short* __restrict__ Ko,
              const short* __restrict__ Vo, const int* __restrict__ Mg,
              float* __restrict__ Og)
{
    __shared__ alignas(128) short Kbuf[2][KVB * DD];   // 8KB each, swizzled bf16 [kv][d]
    __shared__ alignas(128) short Vbuf[2][KVB * DD];   // 8KB each, swizzled bf16 [d][kv]
    __shared__ alignas(128) short PQ[4][16 * 64];      // per-wave Q then P

    const int t = threadIdx.x;
    const int w = t >> 6, l = t & 63, g = l >> 4, n = l & 15;

    const int nb = blockIdx.x, xcd = nb & 7, jj = nb >> 3;
    const int b = xcd + 8 * (jj >> 5), qtl = jj & 31, qbase = qtl * QBLK;

    const float* Qb = Qg + ((size_t)b * LQ + qbase) * DD;
    const char* Ktiles = (const char*)Ko + (size_t)b * 32 * 8192;
    const char* Vtiles = (const char*)Vo + (size_t)b * 32 * 8192;
    const int*  mbase  = Mg + ((size_t)b * LQ + qbase + w * 16 + g * 4) * (size_t)LK + n;

    auto stage = [&](int it2, int sel) {
        const char* ksrc = Ktiles + (size_t)it2 * 8192;
        const char* vsrc = Vtiles + (size_t)it2 * 8192;
        #pragma unroll
        for (int j2 = 0; j2 < 2; ++j2) {
            int ch = w * 2 + j2;
            glds16(ksrc + ch * 1024 + l * 16, (char*)&Kbuf[sel][0] + ch * 1024);
            glds16(vsrc + ch * 1024 + l * 16, (char*)&Vbuf[sel][0] + ch * 1024);
        }
    };

    int mv[16];
    auto mload = [&](int it2) {
        #pragma unroll
        for (int r = 0; r < 4; ++r)
            #pragma unroll
            for (int c = 0; c < 4; ++c)
                mv[r * 4 + c] = mbase[(size_t)r * LK + it2 * 64 + c * 16];
    };

    // ---- prologue: Q loads first (oldest), then tile-0 staging in flight ----
    const int qr = t >> 2, db = (t & 3) * 16;
    f32x4 q0[4];
    #pragma unroll
    for (int k2 = 0; k2 < 4; ++k2)
        q0[k2] = *(const f32x4*)(Qb + (size_t)qr * DD + db + k2 * 4);

    stage(0, 0);
    mload(0);
    asm volatile("" ::: "memory");       // pin issue point

    {   // Q f32 -> bf16 into PQ (wave-local rows)
        short* rowp = &PQ[qr >> 4][(qr & 15) * 64];
        #pragma unroll
        for (int k2 = 0; k2 < 4; ++k2) {
            int dd = db + k2 * 4;
            short4v qp;
            qp.x = bfs(q0[k2].x); qp.y = bfs(q0[k2].y);
            qp.z = bfs(q0[k2].z); qp.w = bfs(q0[k2].w);
            *(short4v*)((char*)rowp + ((dd * 2) ^ ((qr & 7) << 4))) = qp;
        }
    }
    short8 aQ[2];
    {
        short* rowp = &PQ[w][n * 64];
        #pragma unroll
        for (int s2 = 0; s2 < 2; ++s2)
            aQ[s2] = *(short8*)((char*)rowp + ((s2 * 64 + g * 16) ^ ((n & 7) << 4)));
    }

    f32x4 Oacc[4];
    #pragma unroll
    for (int c = 0; c < 4; ++c) { Oacc[c].x = 0.f; Oacc[c].y = 0.f; Oacc[c].z = 0.f; Oacc[c].w = 0.f; }
    float m2[4]   = { -1e30f, -1e30f, -1e30f, -1e30f };
    float lsum[4] = { 0.f, 0.f, 0.f, 0.f };
    const float SC2 = 0.125f * 1.4426950408889634f;
    short* Pw = &PQ[w][0];

    for (int it = 0; it < NIT; ++it) {
        const int cur = it & 1;
        __builtin_amdgcn_s_barrier();                      // raw: no vmcnt drain
        asm volatile("s_waitcnt vmcnt(0)" ::: "memory");   // tile-it glds + mask arrived (issued 1 iter ago)
        __builtin_amdgcn_sched_barrier(0);

        uint32_t mbits = 0;
        #pragma unroll
        for (int i = 0; i < 16; ++i) mbits |= (mv[i] != 0) ? (1u << i) : 0u;

        const int nx = (it + 1 < NIT) ? it + 1 : NIT - 1;
        stage(nx, cur ^ 1);
        mload(nx);
        asm volatile("" ::: "memory");                     // pin issue point

        const char* Kc = (const char*)&Kbuf[cur][0];
        const char* Vc = (const char*)&Vbuf[cur][0];

        // ---- QK^T ----
        f32x4 S[4];
        #pragma unroll
        for (int c = 0; c < 4; ++c) { S[c].x = 0.f; S[c].y = 0.f; S[c].z = 0.f; S[c].w = 0.f; }
        __builtin_amdgcn_s_setprio(1);
        #pragma unroll
        for (int c = 0; c < 4; ++c) {
            int kvl = c * 16 + n;
            #pragma unroll
            for (int s2 = 0; s2 < 2; ++s2) {
                short8 bk = *(const short8*)(Kc + kvl * 128 + (((s2 * 4 + g) ^ (kvl & 7)) * 16));
                S[c] = __builtin_amdgcn_mfma_f32_16x16x32_bf16(aQ[s2], bk, S[c], 0, 0, 0);
            }
        }
        __builtin_amdgcn_s_setprio(0);

        // ---- mask + scale ----
        #pragma unroll
        for (int c = 0; c < 4; ++c)
            #pragma unroll
            for (int r = 0; r < 4; ++r) {
                float x = S[c][r] * SC2;
                S[c][r] = ((mbits >> (r * 4 + c)) & 1u) ? -1.0e9f : x;
            }

        // ---- online softmax ----
        #pragma unroll
        for (int r = 0; r < 4; ++r) {
            float mx = fmaxf(fmaxf(S[0][r], S[1][r]), fmaxf(S[2][r], S[3][r]));
            mx = rmax16(mx);
            float mnew = fmaxf(m2[r], mx);
            float resc = exp2f(m2[r] - mnew);
            m2[r] = mnew;
            lsum[r] *= resc;
            #pragma unroll
            for (int c = 0; c < 4; ++c) Oacc[c][r] *= resc;

            float rs = 0.f;
            int q_ = g * 4 + r;
            #pragma unroll
            for (int c = 0; c < 4; ++c) {
                float p = exp2f(S[c][r] - mnew);
                rs += p;
                *((short*)((char*)Pw + q_ * 128 + (((c * 16 + n) * 2) ^ ((q_ & 7) << 4)))) = bfs(p);
            }
            lsum[r] += rsum16(rs);
        }

        // ---- PV ----
        __builtin_amdgcn_s_setprio(1);
        #pragma unroll
        for (int ks = 0; ks < 2; ++ks) {
            short8 aP = *(short8*)((char*)Pw + n * 128 + ((ks * 64 + g * 16) ^ ((n & 7) << 4)));
            #pragma unroll
            for (int c = 0; c < 4; ++c) {
                int d = c * 16 + n;
                short8 bv = *(const short8*)(Vc + d * 128 + (((ks * 4 + g) ^ (d & 7)) * 16));
                Oacc[c] = __builtin_amdgcn_mfma_f32_16x16x32_bf16(aP, bv, Oacc[c], 0, 0, 0);
            }
        }
        __builtin_amdgcn_s_setprio(0);
    }

    asm volatile("s_waitcnt vmcnt(0)" ::: "memory");   // drain clamped last prefetch
    #pragma unroll
    for (int r = 0; r < 4; ++r) {
        float inv = 1.0f / lsum[r];
        #pragma unroll
        for (int c = 0; c < 4; ++c)
            Og[((size_t)b * LQ + qbase + w * 16 + g * 4 + r) * DD + c * 16 + n] = Oacc[c][r] * inv;
    }
}

extern "C" void kernel_launch(void* const* d_in, const int* in_sizes, int n_in,
                              void* d_out, int out_size, void* d_ws, size_t ws_size,
                              hipStream_t stream) {
    const float* q = (const float*)d_in[0];
    const float* k = (const float*)d_in[1];
    const float* v = (const float*)d_in[2];
    const int*   m = (const int*)d_in[3];
    float* out = (float*)d_out;
    short* Ko = (short*)d_ws;                          // 4MB swizzled bf16 K tiles
    short* Vo = (short*)((char*)d_ws + (4u << 20));    // 4MB swizzled bf16 V^T tiles

    prep_kv<<<dim3(BZ * (LK / KVB)), dim3(256), 0, stream>>>(k, v, Ko, Vo);
    attn_fwd<<<dim3(BZ * (LQ / QBLK)), dim3(256), 0, stream>>>(q, Ko, Vo, m, out);
}